// Round 1
// baseline (223.864 us; speedup 1.0000x reference)
//
#include <hip/hip_runtime.h>

#define HW_SHIFT 14        // 128*128 = 16384 = 1<<14
#define NUM_ACT 64
#define SPLINE_SIZE 51

__global__ __launch_bounds__(256) void linear_spline_kernel(
    const float4* __restrict__ x4,
    const float* __restrict__ coef,
    const float* __restrict__ scale,
    float4* __restrict__ out4,
    int n4)
{
    int i = blockIdx.x * 256 + threadIdx.x;
    if (i >= n4) return;

    // 4 consecutive elements share the same channel (HW=16384 divisible by 4)
    int elem0 = i << 2;
    int c = (elem0 >> HW_SHIFT) & (NUM_ACT - 1);
    float s = scale[c];
    int zk = c * SPLINE_SIZE + SPLINE_SIZE / 2;   // zero-knot index

    const float grid = 0.16f;      // fp32(2*4/(51-1))
    const float lo   = -4.0f;      // fp32(-0.16*25)
    const float hi   = 3.84f;      // fp32( 0.16*24)

    float4 xv = x4[i];
    float4 ov;

    float xin[4] = {xv.x, xv.y, xv.z, xv.w};
    float xo[4];
#pragma unroll
    for (int k = 0; k < 4; ++k) {
        float xs = xin[k] * s;
        float xc = fminf(fmaxf(xs, lo), hi);
        float fl = floorf(xc / grid);          // IEEE div, matches numpy
        float fr = xs / grid - fl;             // UNclamped xs here
        int idx = zk + (int)fl;
        float c0 = coef[idx];
        float c1 = coef[idx + 1];
        float val = c1 * fr + c0 * (1.0f - fr);
        xo[k] = val / s;
    }
    ov.x = xo[0]; ov.y = xo[1]; ov.z = xo[2]; ov.w = xo[3];
    out4[i] = ov;
}

extern "C" void kernel_launch(void* const* d_in, const int* in_sizes, int n_in,
                              void* d_out, int out_size, void* d_ws, size_t ws_size,
                              hipStream_t stream) {
    const float* x     = (const float*)d_in[0];
    const float* coef  = (const float*)d_in[1];
    const float* scale = (const float*)d_in[2];
    float* out = (float*)d_out;

    int n  = in_sizes[0];          // 32*64*128*128 = 33,554,432
    int n4 = n >> 2;               // 8,388,608 float4 elements
    int block = 256;
    int grid  = (n4 + block - 1) / block;

    linear_spline_kernel<<<grid, block, 0, stream>>>(
        (const float4*)x, coef, scale, (float4*)out, n4);
}

// Round 2
// 223.160 us; speedup vs baseline: 1.0032x; 1.0032x over previous
//
#include <hip/hip_runtime.h>

#define NUM_ACT 64
#define SPLINE_SIZE 51
// x is [32, 64, 128, 128]: H*W = 16384 elems/channel.
// Block = 256 threads x 4 elems = 1024 consecutive elems -> 16 blocks per
// channel exactly, so the channel index is block-uniform.

__global__ __launch_bounds__(256) void linear_spline_kernel(
    const float4* __restrict__ x4,
    const float* __restrict__ coef,
    const float* __restrict__ scale,
    float4* __restrict__ out4)
{
    __shared__ float lcoef[SPLINE_SIZE];

    int c = (blockIdx.x >> 4) & (NUM_ACT - 1);   // block-uniform channel

    if (threadIdx.x < SPLINE_SIZE)
        lcoef[threadIdx.x] = coef[c * SPLINE_SIZE + threadIdx.x];

    float s  = scale[c];        // scalar load (c is SGPR)
    float rs = 1.0f / s;        // one divide per thread; s==1.0f in practice

    __syncthreads();

    int i = blockIdx.x * 256 + threadIdx.x;

    const float inv_grid = 6.25f;   // == fl(1/0.16f) exactly

    float4 xv = x4[i];
    float xin[4] = {xv.x, xv.y, xv.z, xv.w};
    float xo[4];
#pragma unroll
    for (int k = 0; k < 4; ++k) {
        float xs = xin[k] * s;
        float t  = xs * inv_grid;
        // clamp-then-floor == floor-then-int-clamp (matches reference at the
        // clamp boundaries; interior 1-ulp floor flips are continuous -> safe)
        int fl = (int)floorf(t);
        fl = min(max(fl, -(SPLINE_SIZE / 2)), SPLINE_SIZE / 2 - 1); // [-25, 24]
        float fr = t - (float)fl;             // fracs from UNclamped xs
        int li = fl + SPLINE_SIZE / 2;        // [0, 49]
        float c0 = lcoef[li];
        float c1 = lcoef[li + 1];
        float val = c1 * fr + c0 * (1.0f - fr);
        xo[k] = val * rs;
    }
    float4 ov;
    ov.x = xo[0]; ov.y = xo[1]; ov.z = xo[2]; ov.w = xo[3];
    out4[i] = ov;
}

extern "C" void kernel_launch(void* const* d_in, const int* in_sizes, int n_in,
                              void* d_out, int out_size, void* d_ws, size_t ws_size,
                              hipStream_t stream) {
    const float* x     = (const float*)d_in[0];
    const float* coef  = (const float*)d_in[1];
    const float* scale = (const float*)d_in[2];
    float* out = (float*)d_out;

    int n  = in_sizes[0];          // 33,554,432 (divisible by 1024)
    int n4 = n >> 2;               // 8,388,608 float4s
    int grid = n4 / 256;           // 32768 blocks, exact

    linear_spline_kernel<<<grid, 256, 0, stream>>>(
        (const float4*)x, coef, scale, (float4*)out);
}

// Round 4
// 221.444 us; speedup vs baseline: 1.0109x; 1.0077x over previous
//
#include <hip/hip_runtime.h>

#define NUM_ACT 64
#define SPLINE_SIZE 51
// x is [32, 64, 128, 128]: H*W = 16384 elems/channel.
// Block = 256 threads x 8 elems (2 float4s, contiguous at block level)
// = 2048 consecutive elems -> exactly 8 blocks per channel, so the channel
// index is block-uniform.

typedef float f32x4 __attribute__((ext_vector_type(4)));  // native vec for nontemporal builtins

__global__ __launch_bounds__(256) void linear_spline_kernel(
    const f32x4* __restrict__ x4,
    const float* __restrict__ coef,
    const float* __restrict__ scale,
    f32x4* __restrict__ out4)
{
    __shared__ float lcoef[SPLINE_SIZE];

    int c = (blockIdx.x >> 3) & (NUM_ACT - 1);   // block-uniform channel

    if (threadIdx.x < SPLINE_SIZE)
        lcoef[threadIdx.x] = coef[c * SPLINE_SIZE + threadIdx.x];

    float s  = scale[c];        // scalar load (c is SGPR-uniform)
    float rs = 1.0f / s;

    __syncthreads();

    const float inv_grid = 6.25f;   // == fl(1/0.16f) exactly

    int base = blockIdx.x * 512 + threadIdx.x;   // two float4s: base, base+256

#pragma unroll
    for (int j = 0; j < 2; ++j) {
        int i = base + j * 256;
        f32x4 xv = __builtin_nontemporal_load(&x4[i]);
        f32x4 ov;
#pragma unroll
        for (int k = 0; k < 4; ++k) {
            float xs = xv[k] * s;
            float t  = xs * inv_grid;
            // floor-then-int-clamp == reference's clamp-then-floor at the
            // boundaries (xs>3.84 -> t>=24.000001 -> fl=24; xs<-4 -> clamp -25);
            // interior 1-ulp floor flips are continuous -> harmless.
            int fl = (int)floorf(t);
            fl = min(max(fl, -(SPLINE_SIZE / 2)), SPLINE_SIZE / 2 - 1); // [-25,24]
            float fr = t - (float)fl;          // fracs from UNclamped xs
            int li = fl + SPLINE_SIZE / 2;     // [0, 49]
            float c0 = lcoef[li];
            float c1 = lcoef[li + 1];
            ov[k] = (c1 * fr + c0 * (1.0f - fr)) * rs;
        }
        __builtin_nontemporal_store(ov, &out4[i]);
    }
}

extern "C" void kernel_launch(void* const* d_in, const int* in_sizes, int n_in,
                              void* d_out, int out_size, void* d_ws, size_t ws_size,
                              hipStream_t stream) {
    const float* x     = (const float*)d_in[0];
    const float* coef  = (const float*)d_in[1];
    const float* scale = (const float*)d_in[2];
    float* out = (float*)d_out;

    int n  = in_sizes[0];          // 33,554,432 (divisible by 2048)
    int n4 = n >> 2;               // 8,388,608 float4s
    int grid = n4 / 512;           // 16384 blocks, exact

    linear_spline_kernel<<<grid, 256, 0, stream>>>(
        (const f32x4*)x, coef, scale, (f32x4*)out);
}